// Round 4
// baseline (21086.456 us; speedup 1.0000x reference)
//
#include <hip/hip_runtime.h>

// TinyRNNPolicy: h_{t+1} = tanh(W h_t); action_t = tanh(mean(h_{t+1}[:2048]))
//
// R4: persistent kernel, 256 blocks x 512 threads (1 block/CU, 8 waves).
// __launch_bounds__(512,2) -> 256 VGPR/thread budget (unified VGPR+AGPR).
// W slice = 16 rows x 4096 per block, 128 floats/thread, pinned in registers;
// sched_barrier(0) every 16 cols caps transient LDS-load pressure so the
// allocator never spills the long-lived W values (R3 failure mode: 128-reg
// cap, w[] split to scratch -> 64 MB/step refetch from L2/L3).
// Cross-block data via relaxed agent-scope atomics (no fences). Barrier:
// wave-0 vmcnt-drain + flag store, per-lane spin (t<256), one __syncthreads.

#define N 4096
#define HALF 2048
#define BLOCKS 256
#define TPB 512
#define RPB 16        // rows per block
#define CCOLS 128     // cols per thread-chunk
#define NCH 32        // chunks (4096/128)
#define PAD 132       // LDS chunk stride (132%32==4 -> conflict-free groups)

// ws layout (dword offsets); ws re-poisoned 0xAA each launch -> init kernel.
#define WS_FLAGS 0            // 256 flags, stride 16 dwords (64B lines)
#define WS_HA    4096         // h ping
#define WS_HB    8192         // h pong
#define WS_ACC   12288        // accum[out_size] (fallback path only)
#define WS_PART  16384        // parts[n_steps*128] (big path)

__device__ __forceinline__ float agent_ld(const float* p) {
    return __hip_atomic_load(p, __ATOMIC_RELAXED, __HIP_MEMORY_SCOPE_AGENT);
}
__device__ __forceinline__ void agent_st(float* p, float v) {
    __hip_atomic_store(p, v, __ATOMIC_RELAXED, __HIP_MEMORY_SCOPE_AGENT);
}
__device__ __forceinline__ unsigned agent_ldu(const unsigned* p) {
    return __hip_atomic_load(p, __ATOMIC_RELAXED, __HIP_MEMORY_SCOPE_AGENT);
}
__device__ __forceinline__ void agent_stu(unsigned* p, unsigned v) {
    __hip_atomic_store(p, v, __ATOMIC_RELAXED, __HIP_MEMORY_SCOPE_AGENT);
}

__device__ __forceinline__ float tanh_fast(float x) {
    x = fminf(fmaxf(x, -15.0f), 15.0f);   // clamp avoids inf/inf
    float e = __expf(2.0f * x);
    return (e - 1.0f) / (e + 1.0f);       // exact 0 at x==0
}

__global__ void rnn_init(const float* __restrict__ h0, float* __restrict__ ws, int n_out) {
    int i = blockIdx.x * blockDim.x + threadIdx.x;
    if (i < BLOCKS * 16) agent_stu((unsigned*)ws + WS_FLAGS + i, 0u);
    if (i < n_out) agent_st(ws + WS_ACC + i, 0.0f);
    if (i < N) agent_st(ws + WS_HA + i, h0[i]);
}

__global__ void __launch_bounds__(TPB, 2)
rnn_persistent(const float* __restrict__ W, const int* __restrict__ pns,
               float* __restrict__ out, float* __restrict__ ws, int big) {
    const int b = blockIdx.x;
    const int t = threadIdx.x;
    const int lane = t & 63;
    const int wave = t >> 6;       // 0..7
    const int row = t & 15;        // row within block's 16 rows
    const int chunk = t >> 4;      // 0..31, 128-col chunk
    const int grow = b * RPB + row;

    // ---- one-time: W slice into registers (128 floats/thread), pinned ----
    float w[CCOLS];
    {
        const float4* Wv = (const float4*)(W + (size_t)grow * N + (size_t)chunk * CCOLS);
#pragma unroll
        for (int i = 0; i < CCOLS / 4; ++i) {
            float4 v = Wv[i];
            w[4*i+0] = v.x; w[4*i+1] = v.y; w[4*i+2] = v.z; w[4*i+3] = v.w;
        }
    }
#pragma unroll
    for (int i = 0; i < CCOLS; ++i) asm volatile("" : "+v"(w[i]));  // block remat

    const int n_steps = *pns;

    __shared__ float hs[NCH * PAD];   // padded h broadcast (~16.5 KiB)
    __shared__ float part[128];       // 8 waves x 16 rows

    unsigned* flags = (unsigned*)ws + WS_FLAGS;
    float* hA    = ws + WS_HA;
    float* hB    = ws + WS_HB;
    float* accum = ws + WS_ACC;
    float* parts = ws + WS_PART;

    for (int s = 0; s < n_steps; ++s) {
        const float* hc = (s & 1) ? hB : hA;
        float*       hn = (s & 1) ? hA : hB;

        // ---- stage h into LDS: 8 floats/thread, padded layout ----
        {
            float h0_ = agent_ld(hc + 8*t + 0);
            float h1_ = agent_ld(hc + 8*t + 1);
            float h2_ = agent_ld(hc + 8*t + 2);
            float h3_ = agent_ld(hc + 8*t + 3);
            float h4_ = agent_ld(hc + 8*t + 4);
            float h5_ = agent_ld(hc + 8*t + 5);
            float h6_ = agent_ld(hc + 8*t + 6);
            float h7_ = agent_ld(hc + 8*t + 7);
            int base = (t >> 4) * PAD + 8 * (t & 15);  // chunk (8t)>>7 = t>>4
            *(float4*)&hs[base + 0] = make_float4(h0_, h1_, h2_, h3_);
            *(float4*)&hs[base + 4] = make_float4(h4_, h5_, h6_, h7_);
        }
        __syncthreads();

        // ---- 128 FMAs over this thread's chunk (16-lane broadcast reads).
        //      sched_barrier every 16 cols: <=4 ds_read_b128 in flight so
        //      transient pressure stays ~16 floats; w[] never spills. ----
        float s0 = 0.f, s1 = 0.f, s2 = 0.f, s3 = 0.f;
        const int hb = chunk * PAD;
#pragma unroll
        for (int g = 0; g < CCOLS / 16; ++g) {
#pragma unroll
            for (int kk = 0; kk < 16; kk += 4) {
                const int k = g * 16 + kk;
                float4 hv = *(const float4*)&hs[hb + k];
                s0 = fmaf(w[k+0], hv.x, s0);
                s1 = fmaf(w[k+1], hv.y, s1);
                s2 = fmaf(w[k+2], hv.z, s2);
                s3 = fmaf(w[k+3], hv.w, s3);
            }
            __builtin_amdgcn_sched_barrier(0);
        }
        float v = (s0 + s1) + (s2 + s3);

        // ---- intra-wave reduce: wave's 4 chunks -> lanes 0..15 (16 rows) ----
        v += __shfl_down(v, 32);
        v += __shfl_down(v, 16);
        if (lane < 16) part[wave * 16 + lane] = v;
        __syncthreads();

        // ---- wave 0: final reduce (8 partials/row), tanh, publish, flag ----
        if (wave == 0) {
            float hval = 0.0f;
            if (t < RPB) {
                float acc = 0.0f;
#pragma unroll
                for (int c = 0; c < TPB / 64; ++c) acc += part[c * 16 + t];
                hval = tanh_fast(acc);
                agent_st(hn + b * RPB + t, hval);    // one 64B line
            }
            // readout partial: sum of this block's 16 h values
            float r = (t < RPB) ? hval : 0.0f;
            r += __shfl_down(r, 8);
            r += __shfl_down(r, 4);
            r += __shfl_down(r, 2);
            r += __shfl_down(r, 1);
            if (t == 0 && b < (BLOCKS / 2)) {
                if (big) agent_st(parts + (size_t)s * 128 + b, r);
                else     atomicAdd(accum + s, r);
            }
            // release: drain this wave's global stores, then publish flag
            asm volatile("s_waitcnt vmcnt(0)" ::: "memory");
            if (t == 0) agent_stu(flags + b * 16, (unsigned)(s + 1));
        }

        // ---- device barrier: per-lane spin on one flag each, then join ----
        if (t < BLOCKS) {
            const unsigned tgt = (unsigned)(s + 1);
            unsigned spins = 0;
            while (agent_ldu(flags + t * 16) < tgt) {
                __builtin_amdgcn_s_sleep(1);
                if (++spins > (1u << 20)) break;   // fail loud, don't hang
            }
        }
        __syncthreads();

        if (!big && b == 0 && t == 0)
            out[s] = tanh_fast(agent_ld(accum + s) * (1.0f / (float)HALF));
    }

    // ---- big path: all outputs computed in parallel after the loop ----
    if (big) {
        const int l = t & 63;
        for (int ss = b * 8 + (t >> 6); ss < n_steps; ss += BLOCKS * 8) {
            float v = agent_ld(parts + (size_t)ss * 128 + l)
                    + agent_ld(parts + (size_t)ss * 128 + 64 + l);
            v += __shfl_down(v, 32);
            v += __shfl_down(v, 16);
            v += __shfl_down(v, 8);
            v += __shfl_down(v, 4);
            v += __shfl_down(v, 2);
            v += __shfl_down(v, 1);
            if (l == 0) out[ss] = tanh_fast(v * (1.0f / (float)HALF));
        }
    }
}

extern "C" void kernel_launch(void* const* d_in, const int* in_sizes, int n_in,
                              void* d_out, int out_size, void* d_ws, size_t ws_size,
                              hipStream_t stream) {
    const float* W  = (const float*)d_in[0];
    const float* h0 = (const float*)d_in[1];
    const int*  pns = (const int*)d_in[2];
    float* out = (float*)d_out;
    float* ws  = (float*)d_ws;

    size_t need = ((size_t)WS_PART + (size_t)out_size * 128) * 4;
    int big = (ws_size >= need) ? 1 : 0;

    int n_init = out_size > N ? out_size : N;
    rnn_init<<<(n_init + 255) / 256, 256, 0, stream>>>(h0, ws, out_size);
    rnn_persistent<<<BLOCKS, TPB, 0, stream>>>(W, pns, out, ws, big);
}

// Round 5
// 20087.439 us; speedup vs baseline: 1.0497x; 1.0497x over previous
//
#include <hip/hip_runtime.h>

// TinyRNNPolicy: h_{t+1} = tanh(W h_t); action_t = tanh(mean(h_{t+1}[:2048]))
//
// R5: persistent kernel, 256 blocks x 512 threads (1 block/CU, 8 waves).
// KEY CHANGE vs R3/R4: W slice (128 floats/thread) lives in AGPRs, held as
// 8 x float16-vectors pinned with "+a" asm INSIDE the step loop. The AGPR
// class has no other users -> allocator cannot be pressured into spilling
// (R2-R4 failure: w[] in arch-VGPR class competed with transients and was
// spilled to scratch -> 64 MB/step refetch, FETCH_SIZE ~750MB, latency-bound).
// gfx950 unified file: VALU reads AGPRs (or compiler inserts v_accvgpr_read).
// Staging uses the one-float4-per-thread LDS write mapping that measured
// ZERO bank conflicts in R2/R3 (two-float4 pattern measured 1.34e8 in R1/R4).

#define N 4096
#define HALF 2048
#define BLOCKS 256
#define TPB 512
#define RPB 16        // rows per block
#define CCOLS 128     // cols per thread-chunk
#define NCH 32        // chunks (4096/128)
#define PAD 132       // LDS chunk stride in floats (132%32==4)

// ws layout (dword offsets); ws re-poisoned 0xAA each launch -> init kernel.
#define WS_FLAGS 0            // 256 flags, stride 16 dwords (64B lines)
#define WS_HA    4096         // h ping
#define WS_HB    8192         // h pong
#define WS_ACC   12288        // accum[out_size] (fallback path only)
#define WS_PART  16384        // parts[n_steps*128] (big path)

typedef float f32x16 __attribute__((ext_vector_type(16)));

__device__ __forceinline__ float agent_ld(const float* p) {
    return __hip_atomic_load(p, __ATOMIC_RELAXED, __HIP_MEMORY_SCOPE_AGENT);
}
__device__ __forceinline__ void agent_st(float* p, float v) {
    __hip_atomic_store(p, v, __ATOMIC_RELAXED, __HIP_MEMORY_SCOPE_AGENT);
}
__device__ __forceinline__ unsigned agent_ldu(const unsigned* p) {
    return __hip_atomic_load(p, __ATOMIC_RELAXED, __HIP_MEMORY_SCOPE_AGENT);
}
__device__ __forceinline__ void agent_stu(unsigned* p, unsigned v) {
    __hip_atomic_store(p, v, __ATOMIC_RELAXED, __HIP_MEMORY_SCOPE_AGENT);
}

__device__ __forceinline__ float tanh_fast(float x) {
    x = fminf(fmaxf(x, -15.0f), 15.0f);   // clamp avoids inf/inf
    float e = __expf(2.0f * x);
    return (e - 1.0f) / (e + 1.0f);       // exact 0 at x==0
}

__global__ void rnn_init(const float* __restrict__ h0, float* __restrict__ ws, int n_out) {
    int i = blockIdx.x * blockDim.x + threadIdx.x;
    if (i < BLOCKS * 16) agent_stu((unsigned*)ws + WS_FLAGS + i, 0u);
    if (i < n_out) agent_st(ws + WS_ACC + i, 0.0f);
    if (i < N) agent_st(ws + WS_HA + i, h0[i]);
}

__global__ void __launch_bounds__(TPB, 2)
rnn_persistent(const float* __restrict__ W, const int* __restrict__ pns,
               float* __restrict__ out, float* __restrict__ ws, int big) {
    const int b = blockIdx.x;
    const int t = threadIdx.x;
    const int lane = t & 63;
    const int wave = t >> 6;       // 0..7
    const int row = t & 15;        // row within block's 16 rows
    const int chunk = t >> 4;      // 0..31, 128-col chunk
    const int grow = b * RPB + row;

    // ---- one-time: W slice (128 floats/thread) -> AGPR-class vectors ----
    f32x16 wa[8];
    {
        const float4* Wv = (const float4*)(W + (size_t)grow * N + (size_t)chunk * CCOLS);
#pragma unroll
        for (int i = 0; i < 8; ++i) {
#pragma unroll
            for (int q = 0; q < 4; ++q) {
                float4 v = Wv[i * 4 + q];
                wa[i][4*q+0] = v.x; wa[i][4*q+1] = v.y;
                wa[i][4*q+2] = v.z; wa[i][4*q+3] = v.w;
            }
        }
    }

    const int n_steps = *pns;

    __shared__ float hs[NCH * PAD];   // padded h broadcast (~16.5 KiB)
    __shared__ float part[128];       // 8 waves x 16 rows

    unsigned* flags = (unsigned*)ws + WS_FLAGS;
    float* hA    = ws + WS_HA;
    float* hB    = ws + WS_HB;
    float* accum = ws + WS_ACC;
    float* parts = ws + WS_PART;

    for (int s = 0; s < n_steps; ++s) {
        // Pin W vectors into AGPRs at every iteration: value appears modified
        // by the asm, so it cannot be rematerialized from memory, and its
        // home register class is AGPR (no competing users -> never spilled).
#pragma unroll
        for (int i = 0; i < 8; ++i) asm volatile("" : "+a"(wa[i]));

        const float* hc = (s & 1) ? hB : hA;
        float*       hn = (s & 1) ? hA : hB;

        // ---- stage h into LDS: one float4 per thread, twice (zero-conflict
        //      mapping measured in R2/R3). element e=4*idx+j -> chunk idx>>5,
        //      offset 4*(idx&31)+j. ----
#pragma unroll
        for (int rep = 0; rep < 2; ++rep) {
            const int idx = t + rep * TPB;          // 0..1023
            float h0_ = agent_ld(hc + 4*idx + 0);
            float h1_ = agent_ld(hc + 4*idx + 1);
            float h2_ = agent_ld(hc + 4*idx + 2);
            float h3_ = agent_ld(hc + 4*idx + 3);
            int base = (idx >> 5) * PAD + 4 * (idx & 31);
            *(float4*)&hs[base] = make_float4(h0_, h1_, h2_, h3_);
        }
        __syncthreads();

        // ---- 128 FMAs over this thread's chunk; W sourced from AGPRs ----
        float s0 = 0.f, s1 = 0.f, s2 = 0.f, s3 = 0.f;
        const int hb = chunk * PAD;
#pragma unroll
        for (int k = 0; k < CCOLS; k += 4) {
            float4 hv = *(const float4*)&hs[hb + k];
            s0 = fmaf(wa[k >> 4][(k & 15) + 0], hv.x, s0);
            s1 = fmaf(wa[k >> 4][(k & 15) + 1], hv.y, s1);
            s2 = fmaf(wa[k >> 4][(k & 15) + 2], hv.z, s2);
            s3 = fmaf(wa[k >> 4][(k & 15) + 3], hv.w, s3);
        }
        float v = (s0 + s1) + (s2 + s3);

        // ---- intra-wave reduce: wave's 4 chunks -> lanes 0..15 (16 rows) ----
        v += __shfl_down(v, 32);
        v += __shfl_down(v, 16);
        if (lane < 16) part[wave * 16 + lane] = v;
        __syncthreads();

        // ---- wave 0: final reduce (8 partials/row), tanh, publish, flag ----
        if (wave == 0) {
            float hval = 0.0f;
            if (t < RPB) {
                float acc = 0.0f;
#pragma unroll
                for (int c = 0; c < TPB / 64; ++c) acc += part[c * 16 + t];
                hval = tanh_fast(acc);
                agent_st(hn + b * RPB + t, hval);    // one 64B line
            }
            // readout partial: sum of this block's 16 h values
            float r = (t < RPB) ? hval : 0.0f;
            r += __shfl_down(r, 8);
            r += __shfl_down(r, 4);
            r += __shfl_down(r, 2);
            r += __shfl_down(r, 1);
            if (t == 0 && b < (BLOCKS / 2)) {
                if (big) agent_st(parts + (size_t)s * 128 + b, r);
                else     atomicAdd(accum + s, r);
            }
            // release: drain this wave's global stores, then publish flag
            asm volatile("s_waitcnt vmcnt(0)" ::: "memory");
            if (t == 0) agent_stu(flags + b * 16, (unsigned)(s + 1));
        }

        // ---- device barrier: per-lane spin on one flag each, then join ----
        if (t < BLOCKS) {
            const unsigned tgt = (unsigned)(s + 1);
            unsigned spins = 0;
            while (agent_ldu(flags + t * 16) < tgt) {
                __builtin_amdgcn_s_sleep(1);
                if (++spins > (1u << 20)) break;   // fail loud, don't hang
            }
        }
        __syncthreads();

        if (!big && b == 0 && t == 0)
            out[s] = tanh_fast(agent_ld(accum + s) * (1.0f / (float)HALF));
    }

    // ---- big path: all outputs computed in parallel after the loop ----
    if (big) {
        const int l = t & 63;
        for (int ss = b * 8 + (t >> 6); ss < n_steps; ss += BLOCKS * 8) {
            float v = agent_ld(parts + (size_t)ss * 128 + l)
                    + agent_ld(parts + (size_t)ss * 128 + 64 + l);
            v += __shfl_down(v, 32);
            v += __shfl_down(v, 16);
            v += __shfl_down(v, 8);
            v += __shfl_down(v, 4);
            v += __shfl_down(v, 2);
            v += __shfl_down(v, 1);
            if (l == 0) out[ss] = tanh_fast(v * (1.0f / (float)HALF));
        }
    }
}

extern "C" void kernel_launch(void* const* d_in, const int* in_sizes, int n_in,
                              void* d_out, int out_size, void* d_ws, size_t ws_size,
                              hipStream_t stream) {
    const float* W  = (const float*)d_in[0];
    const float* h0 = (const float*)d_in[1];
    const int*  pns = (const int*)d_in[2];
    float* out = (float*)d_out;
    float* ws  = (float*)d_ws;

    size_t need = ((size_t)WS_PART + (size_t)out_size * 128) * 4;
    int big = (ws_size >= need) ? 1 : 0;

    int n_init = out_size > N ? out_size : N;
    rnn_init<<<(n_init + 255) / 256, 256, 0, stream>>>(h0, ws, out_size);
    rnn_persistent<<<BLOCKS, TPB, 0, stream>>>(W, pns, out, ws, big);
}